// Round 1
// baseline (1279.132 us; speedup 1.0000x reference)
//
#include <hip/hip_runtime.h>
#include <hip/hip_bf16.h>

#define D 512
#define BM 64
#define BN 64
#define BK 32

typedef __attribute__((ext_vector_type(8))) short bf16x8;
typedef __attribute__((ext_vector_type(4))) float f32x4;

// round-to-nearest-even fp32 -> bf16, two packed into a uint
__device__ __forceinline__ unsigned int pack2_bf16(float a, float b) {
    union { float f; unsigned u; } ua, ub;
    ua.f = a; ub.f = b;
    unsigned ra = (ua.u + 0x7FFFu + ((ua.u >> 16) & 1u)) >> 16;
    unsigned rb = (ub.u + 0x7FFFu + ((ub.u >> 16) & 1u)) >> 16;
    return ra | (rb << 16);
}

// One block (128 threads) per edge: read 512-float src row as float4,
// atomically accumulate into agg[dst].
__global__ __launch_bounds__(128) void scatter_add_kernel(
    const float* __restrict__ src_h,
    const int* __restrict__ src_idx,
    const int* __restrict__ dst_idx,
    float* __restrict__ agg)
{
    const int e = blockIdx.x;
    const int s = src_idx[e];
    const int d = dst_idx[e];
    const float4* srow = (const float4*)(src_h + (size_t)s * D);
    float4 v = srow[threadIdx.x];
    float* drow = agg + (size_t)d * D + threadIdx.x * 4;
    unsafeAtomicAdd(drow + 0, v.x);
    unsafeAtomicAdd(drow + 1, v.y);
    unsafeAtomicAdd(drow + 2, v.z);
    unsafeAtomicAdd(drow + 3, v.w);
}

// out[m,n] = sum_k agg[m,k] * W[n,k] + b[n]
// bf16 MFMA 16x16x32, 64x64 block tile, 4 waves in 2x2, each wave 32x32.
__global__ __launch_bounds__(256) void gemm_bias_kernel(
    const float* __restrict__ A,      // [M, D] fp32 (agg)
    const float* __restrict__ Wm,     // [D, D] fp32, row-major [n][k]
    const float* __restrict__ bias,   // [D]
    float* __restrict__ out,          // [M, D]
    int M)
{
    __shared__ __align__(16) unsigned short As[BM * BK];
    __shared__ __align__(16) unsigned short Bs[BN * BK];

    const int tid  = threadIdx.x;
    const int lane = tid & 63;
    const int wave = tid >> 6;
    const int wm   = wave >> 1;       // 0..1 : wave row
    const int wn   = wave & 1;        // 0..1 : wave col
    const int quad = lane >> 4;       // 0..3
    const int lr   = lane & 15;       // 0..15
    const int m0   = blockIdx.y * BM;
    const int n0   = blockIdx.x * BN;

    // staging assignment: each thread loads 8 consecutive k-elems of one row
    const int srow = (tid * 8) >> 5;  // 0..63
    const int scol = (tid * 8) & 31;  // 0,8,16,24

    f32x4 acc[2][2] = {};

    for (int k0 = 0; k0 < D; k0 += BK) {
        // ---- stage A (with M guard on the tail tile) ----
        float4 x = {0.f, 0.f, 0.f, 0.f}, y = {0.f, 0.f, 0.f, 0.f};
        const int gr = m0 + srow;
        if (gr < M) {
            const float* gp = A + (size_t)gr * D + k0 + scol;
            x = *(const float4*)gp;
            y = *(const float4*)(gp + 4);
        }
        uint4 pa;
        pa.x = pack2_bf16(x.x, x.y); pa.y = pack2_bf16(x.z, x.w);
        pa.z = pack2_bf16(y.x, y.y); pa.w = pack2_bf16(y.z, y.w);

        // ---- stage B (W rows, n0+srow always < 512) ----
        const float* wp = Wm + (size_t)(n0 + srow) * D + k0 + scol;
        float4 wx = *(const float4*)wp;
        float4 wy = *(const float4*)(wp + 4);
        uint4 pb;
        pb.x = pack2_bf16(wx.x, wx.y); pb.y = pack2_bf16(wx.z, wx.w);
        pb.z = pack2_bf16(wy.x, wy.y); pb.w = pack2_bf16(wy.z, wy.w);

        *(uint4*)&As[srow * BK + scol] = pa;
        *(uint4*)&Bs[srow * BK + scol] = pb;
        __syncthreads();

        // ---- MFMA: wave computes 32x32 via 2x2 tiles of 16x16 ----
        bf16x8 a0 = *(const bf16x8*)&As[(wm * 32      + lr) * BK + quad * 8];
        bf16x8 a1 = *(const bf16x8*)&As[(wm * 32 + 16 + lr) * BK + quad * 8];
        bf16x8 b0 = *(const bf16x8*)&Bs[(wn * 32      + lr) * BK + quad * 8];
        bf16x8 b1 = *(const bf16x8*)&Bs[(wn * 32 + 16 + lr) * BK + quad * 8];

        acc[0][0] = __builtin_amdgcn_mfma_f32_16x16x32_bf16(a0, b0, acc[0][0], 0, 0, 0);
        acc[0][1] = __builtin_amdgcn_mfma_f32_16x16x32_bf16(a0, b1, acc[0][1], 0, 0, 0);
        acc[1][0] = __builtin_amdgcn_mfma_f32_16x16x32_bf16(a1, b0, acc[1][0], 0, 0, 0);
        acc[1][1] = __builtin_amdgcn_mfma_f32_16x16x32_bf16(a1, b1, acc[1][1], 0, 0, 0);
        __syncthreads();
    }

    // ---- epilogue: C/D layout col=lane&15, row=quad*4+i ----
    #pragma unroll
    for (int ti = 0; ti < 2; ++ti) {
        #pragma unroll
        for (int tj = 0; tj < 2; ++tj) {
            const int col = n0 + wn * 32 + tj * 16 + lr;
            const float bv = bias[col];
            const int rbase = m0 + wm * 32 + ti * 16 + quad * 4;
            #pragma unroll
            for (int i = 0; i < 4; ++i) {
                const int r = rbase + i;
                if (r < M) out[(size_t)r * D + col] = acc[ti][tj][i] + bv;
            }
        }
    }
}

extern "C" void kernel_launch(void* const* d_in, const int* in_sizes, int n_in,
                              void* d_out, int out_size, void* d_ws, size_t ws_size,
                              hipStream_t stream) {
    const float* src_h  = (const float*)d_in[0];
    const float* W      = (const float*)d_in[1];
    const float* b      = (const float*)d_in[2];
    const int*   si     = (const int*)d_in[3];
    const int*   di     = (const int*)d_in[4];
    // d_in[5] = n_dst scalar; derive sizes from in_sizes instead
    const int M = in_sizes[0] / D;   // 50000
    const int E = in_sizes[3];       // 150000

    float* agg = (float*)d_ws;       // [M, D] fp32 accumulator

    hipMemsetAsync(agg, 0, (size_t)M * D * sizeof(float), stream);

    scatter_add_kernel<<<dim3(E), dim3(128), 0, stream>>>(src_h, si, di, agg);

    dim3 grid(D / BN, (M + BM - 1) / BM);
    gemm_bias_kernel<<<grid, dim3(256), 0, stream>>>(agg, W, b, (float*)d_out, M);
}

// Round 2
// 411.150 us; speedup vs baseline: 3.1111x; 3.1111x over previous
//
#include <hip/hip_runtime.h>
#include <hip/hip_bf16.h>

#define D 512
#define BM 128
#define BN 128
#define BK 32
#define SCAN_T 1024

typedef __attribute__((ext_vector_type(8))) short bf16x8;
typedef __attribute__((ext_vector_type(4))) float f32x4;

__device__ __forceinline__ unsigned short bf16_rne(float f) {
    union { float f; unsigned u; } v; v.f = f;
    return (unsigned short)((v.u + 0x7FFFu + ((v.u >> 16) & 1u)) >> 16);
}

// async global -> LDS, 16 bytes per lane. LDS side must be wave-uniform base + lane*16.
__device__ __forceinline__ void gload16(const void* g, void* l) {
    __builtin_amdgcn_global_load_lds(
        (const __attribute__((address_space(1))) void*)g,
        (__attribute__((address_space(3))) void*)l,
        16, 0, 0);
}

// ---------------- CSR build ----------------

__global__ __launch_bounds__(256) void hist_kernel(const int* __restrict__ dst, int E,
                                                   int* __restrict__ cnt) {
    int e = blockIdx.x * 256 + threadIdx.x;
    if (e < E) atomicAdd(&cnt[dst[e]], 1);
}

// single-block exclusive scan over cnt[0..M); writes offsets[0..M] and resets cnt to
// per-node start offsets (cursor for the sort pass).
__global__ __launch_bounds__(SCAN_T) void scan_kernel(int* __restrict__ cnt,
                                                      int* __restrict__ offsets, int M) {
    __shared__ int sdata[SCAN_T];
    const int t = threadIdx.x;
    const int chunk = (M + SCAN_T - 1) / SCAN_T;
    const int lo = t * chunk;
    const int hi = min(lo + chunk, M);
    int total = 0;
    for (int i = lo; i < hi; ++i) total += cnt[i];
    sdata[t] = total;
    __syncthreads();
    for (int ofs = 1; ofs < SCAN_T; ofs <<= 1) {
        int v = (t >= ofs) ? sdata[t - ofs] : 0;
        __syncthreads();
        sdata[t] += v;
        __syncthreads();
    }
    int run = sdata[t] - total;  // exclusive base for this thread's chunk
    for (int i = lo; i < hi; ++i) {
        int c = cnt[i];
        offsets[i] = run;
        cnt[i] = run;
        run += c;
    }
    if (t == SCAN_T - 1) offsets[M] = sdata[SCAN_T - 1];
}

__global__ __launch_bounds__(256) void sort_kernel(const int* __restrict__ src,
                                                   const int* __restrict__ dst, int E,
                                                   int* __restrict__ cursor,
                                                   int* __restrict__ sorted_src) {
    int e = blockIdx.x * 256 + threadIdx.x;
    if (e < E) {
        int pos = atomicAdd(&cursor[dst[e]], 1);
        sorted_src[pos] = src[e];
    }
}

// ---------------- gather-aggregate (no atomics), fp32 acc -> bf16 write ----------------

__global__ __launch_bounds__(128) void agg_kernel(const float* __restrict__ src_h,
                                                  const int* __restrict__ offsets,
                                                  const int* __restrict__ sorted_src,
                                                  unsigned short* __restrict__ aggb) {
    const int d = blockIdx.x;
    const int t = threadIdx.x;
    const int beg = offsets[d];
    const int end = offsets[d + 1];
    float4 acc = {0.f, 0.f, 0.f, 0.f};
    for (int e = beg; e < end; ++e) {
        const int s = sorted_src[e];
        float4 v = ((const float4*)(src_h + (size_t)s * D))[t];
        acc.x += v.x; acc.y += v.y; acc.z += v.z; acc.w += v.w;
    }
    ushort4 o;
    o.x = bf16_rne(acc.x); o.y = bf16_rne(acc.y);
    o.z = bf16_rne(acc.z); o.w = bf16_rne(acc.w);
    *(ushort4*)(aggb + (size_t)d * D + t * 4) = o;
}

// ---------------- W fp32 -> bf16 ----------------

__global__ __launch_bounds__(256) void wconv_kernel(const float* __restrict__ W,
                                                    unsigned short* __restrict__ wb) {
    int i = blockIdx.x * 256 + threadIdx.x;  // over D*D/2 float2 pairs
    float2 v = ((const float2*)W)[i];
    unsigned r = ((unsigned)bf16_rne(v.x)) | (((unsigned)bf16_rne(v.y)) << 16);
    ((unsigned*)wb)[i] = r;
}

// ---------------- GEMM: out = aggb @ wb^T + bias (m97-style 128x128 tile) ----------------

__global__ __launch_bounds__(256) void gemm_kernel(const unsigned short* __restrict__ A,
                                                   const unsigned short* __restrict__ B,
                                                   const float* __restrict__ bias,
                                                   float* __restrict__ out, int M) {
    __shared__ __align__(16) unsigned short As[BM * BK];  // 8 KB
    __shared__ __align__(16) unsigned short Bs[BN * BK];  // 8 KB

    const int t = threadIdx.x;
    const int lane = t & 63;
    const int wave = t >> 6;
    const int wm = wave >> 1;   // wave row (0..1)
    const int wn = wave & 1;    // wave col (0..1)
    const int quad = lane >> 4; // 0..3
    const int lr = lane & 15;   // 0..15
    const int m0 = blockIdx.y * BM;
    const int n0 = blockIdx.x * BN;

    // staging: thread t loads 8 bf16 (16 B); row = t>>2, k-chunk = t&3
    const int srow = t >> 2;
    const int scol = (t & 3) * 8;
    const int arow0 = min(m0 + srow, M - 1);        // clamp tail: garbage rows are discarded
    const int arow1 = min(m0 + 64 + srow, M - 1);
    const int brow0 = n0 + srow;                    // always < 512
    const int brow1 = n0 + 64 + srow;

    f32x4 acc[4][4] = {};

    for (int k0 = 0; k0 < D; k0 += BK) {
        gload16(A + (size_t)arow0 * D + k0 + scol, As + t * 8);
        gload16(A + (size_t)arow1 * D + k0 + scol, As + 2048 + t * 8);
        gload16(B + (size_t)brow0 * D + k0 + scol, Bs + t * 8);
        gload16(B + (size_t)brow1 * D + k0 + scol, Bs + 2048 + t * 8);
        __syncthreads();

        bf16x8 af[4], bfr[4];
        #pragma unroll
        for (int i = 0; i < 4; ++i) {
            af[i]  = *(const bf16x8*)&As[(wm * 64 + i * 16 + lr) * BK + quad * 8];
            bfr[i] = *(const bf16x8*)&Bs[(wn * 64 + i * 16 + lr) * BK + quad * 8];
        }
        #pragma unroll
        for (int i = 0; i < 4; ++i)
            #pragma unroll
            for (int j = 0; j < 4; ++j)
                acc[i][j] = __builtin_amdgcn_mfma_f32_16x16x32_bf16(af[i], bfr[j], acc[i][j], 0, 0, 0);
        __syncthreads();
    }

    // epilogue: C/D layout col = lane&15, row = quad*4 + reg
    #pragma unroll
    for (int j = 0; j < 4; ++j) {
        const int col = n0 + wn * 64 + j * 16 + lr;
        const float bv = bias[col];
        #pragma unroll
        for (int i = 0; i < 4; ++i) {
            const int rbase = m0 + wm * 64 + i * 16 + quad * 4;
            #pragma unroll
            for (int r = 0; r < 4; ++r) {
                const int row = rbase + r;
                if (row < M) out[(size_t)row * D + col] = acc[i][j][r] + bv;
            }
        }
    }
}

extern "C" void kernel_launch(void* const* d_in, const int* in_sizes, int n_in,
                              void* d_out, int out_size, void* d_ws, size_t ws_size,
                              hipStream_t stream) {
    const float* src_h = (const float*)d_in[0];
    const float* W     = (const float*)d_in[1];
    const float* b     = (const float*)d_in[2];
    const int*   si    = (const int*)d_in[3];
    const int*   di    = (const int*)d_in[4];
    const int M = in_sizes[0] / D;   // 50000
    const int E = in_sizes[3];       // 150000

    char* ws = (char*)d_ws;
    unsigned short* aggb = (unsigned short*)ws;                    // M*D*2   = 51,200,000 B
    unsigned short* wb   = (unsigned short*)(ws + 51200000);       // D*D*2   = 524,288 B
    int* offsets         = (int*)(ws + 51724288);                  // (M+1)*4 = 200,004 B
    int* cnt             = (int*)(ws + 51924480);                  // M*4     = 200,000 B
    int* ssrc            = (int*)(ws + 52124480);                  // E*4     = 600,000 B
                                                                   // total ~52.8 MB (< proven ws)

    hipMemsetAsync(cnt, 0, (size_t)M * sizeof(int), stream);
    wconv_kernel<<<dim3((D * D / 2) / 256), 256, 0, stream>>>(W, wb);
    hist_kernel<<<dim3((E + 255) / 256), 256, 0, stream>>>(di, E, cnt);
    scan_kernel<<<1, SCAN_T, 0, stream>>>(cnt, offsets, M);
    sort_kernel<<<dim3((E + 255) / 256), 256, 0, stream>>>(si, di, E, cnt, ssrc);
    agg_kernel<<<dim3(M), 128, 0, stream>>>(src_h, offsets, ssrc, aggb);
    gemm_kernel<<<dim3(D / BN, (M + BM - 1) / BM), 256, 0, stream>>>(aggb, wb, b, (float*)d_out, M);
}

// Round 3
// 314.000 us; speedup vs baseline: 4.0737x; 1.3094x over previous
//
#include <hip/hip_runtime.h>
#include <hip/hip_bf16.h>

#define D 512
#define BM 128
#define BN 128
#define BK 32
#define SB 512          // elements per scan block

typedef __attribute__((ext_vector_type(8))) short bf16x8;
typedef __attribute__((ext_vector_type(4))) float f32x4;

__device__ __forceinline__ unsigned short bf16_rne(float f) {
    union { float f; unsigned u; } v; v.f = f;
    return (unsigned short)((v.u + 0x7FFFu + ((v.u >> 16) & 1u)) >> 16);
}

__device__ __forceinline__ void gload16(const void* g, void* l) {
    __builtin_amdgcn_global_load_lds(
        (const __attribute__((address_space(1))) void*)g,
        (__attribute__((address_space(3))) void*)l,
        16, 0, 0);
}

// ---------------- CSR build ----------------

__global__ __launch_bounds__(256) void hist_kernel(const int* __restrict__ dst, int E,
                                                   int* __restrict__ cnt) {
    int e = blockIdx.x * 256 + threadIdx.x;
    if (e < E) atomicAdd(&cnt[dst[e]], 1);
}

// stage 1: per-block (512 elems) totals
__global__ __launch_bounds__(256) void scan_reduce_kernel(const int* __restrict__ cnt, int M,
                                                          int* __restrict__ bsum) {
    const int t = threadIdx.x;
    const int i0 = blockIdx.x * SB + t * 2;
    int v = 0;
    if (i0 < M)     v += cnt[i0];
    if (i0 + 1 < M) v += cnt[i0 + 1];
    #pragma unroll
    for (int o = 32; o > 0; o >>= 1) v += __shfl_down(v, o, 64);
    __shared__ int ws_[4];
    if ((t & 63) == 0) ws_[t >> 6] = v;
    __syncthreads();
    if (t == 0) bsum[blockIdx.x] = ws_[0] + ws_[1] + ws_[2] + ws_[3];
}

// stage 2: single tiny block scans the (<=256) block sums; writes grand total to offsets[M]
__global__ __launch_bounds__(256) void scan_bsum_kernel(const int* __restrict__ bsum, int NB,
                                                        int* __restrict__ bscan,
                                                        int* __restrict__ offsets, int M) {
    __shared__ int s[256];
    const int t = threadIdx.x;
    int v = (t < NB) ? bsum[t] : 0;
    s[t] = v;
    __syncthreads();
    #pragma unroll
    for (int o = 1; o < 256; o <<= 1) {
        int u = (t >= o) ? s[t - o] : 0;
        __syncthreads();
        s[t] += u;
        __syncthreads();
    }
    if (t < NB) bscan[t] = s[t] - v;          // exclusive
    if (t == 255) offsets[M] = s[255];        // grand total (== E)
}

// stage 3: per-block exclusive scan + block base; writes offsets[] and cursor (cnt)
__global__ __launch_bounds__(256) void scan_final_kernel(int* __restrict__ cnt, int M,
                                                         const int* __restrict__ bscan,
                                                         int* __restrict__ offsets) {
    __shared__ int s[256];
    const int t = threadIdx.x;
    const int base = blockIdx.x * SB + t * 2;
    int a = (base < M) ? cnt[base] : 0;
    int b = (base + 1 < M) ? cnt[base + 1] : 0;
    const int tsum = a + b;
    s[t] = tsum;
    __syncthreads();
    #pragma unroll
    for (int o = 1; o < 256; o <<= 1) {
        int u = (t >= o) ? s[t - o] : 0;
        __syncthreads();
        s[t] += u;
        __syncthreads();
    }
    const int excl = s[t] - tsum + bscan[blockIdx.x];
    if (base < M)     { offsets[base] = excl;         cnt[base] = excl; }
    if (base + 1 < M) { offsets[base + 1] = excl + a; cnt[base + 1] = excl + a; }
}

__global__ __launch_bounds__(256) void sort_kernel(const int* __restrict__ src,
                                                   const int* __restrict__ dst, int E,
                                                   int* __restrict__ cursor,
                                                   int* __restrict__ sorted_src) {
    int e = blockIdx.x * 256 + threadIdx.x;
    if (e < E) {
        int pos = atomicAdd(&cursor[dst[e]], 1);
        sorted_src[pos] = src[e];
    }
}

// ---------------- gather-aggregate (no atomics), fp32 acc -> bf16 write ----------------

__global__ __launch_bounds__(128) void agg_kernel(const float* __restrict__ src_h,
                                                  const int* __restrict__ offsets,
                                                  const int* __restrict__ sorted_src,
                                                  unsigned short* __restrict__ aggb) {
    const int d = blockIdx.x;
    const int t = threadIdx.x;
    const int beg = offsets[d];
    const int end = offsets[d + 1];
    float4 acc = {0.f, 0.f, 0.f, 0.f};
    for (int e = beg; e < end; ++e) {
        const int s = sorted_src[e];
        float4 v = ((const float4*)(src_h + (size_t)s * D))[t];
        acc.x += v.x; acc.y += v.y; acc.z += v.z; acc.w += v.w;
    }
    ushort4 o;
    o.x = bf16_rne(acc.x); o.y = bf16_rne(acc.y);
    o.z = bf16_rne(acc.z); o.w = bf16_rne(acc.w);
    *(ushort4*)(aggb + (size_t)d * D + t * 4) = o;
}

// ---------------- W fp32 -> bf16 ----------------

__global__ __launch_bounds__(256) void wconv_kernel(const float* __restrict__ W,
                                                    unsigned short* __restrict__ wb) {
    int i = blockIdx.x * 256 + threadIdx.x;
    float2 v = ((const float2*)W)[i];
    unsigned r = ((unsigned)bf16_rne(v.x)) | (((unsigned)bf16_rne(v.y)) << 16);
    ((unsigned*)wb)[i] = r;
}

// ---------------- GEMM: out = aggb @ wb^T + bias ----------------

__global__ __launch_bounds__(256) void gemm_kernel(const unsigned short* __restrict__ A,
                                                   const unsigned short* __restrict__ B,
                                                   const float* __restrict__ bias,
                                                   float* __restrict__ out, int M) {
    __shared__ __align__(16) unsigned short As[BM * BK];
    __shared__ __align__(16) unsigned short Bs[BN * BK];

    const int t = threadIdx.x;
    const int lane = t & 63;
    const int wave = t >> 6;
    const int wm = wave >> 1;
    const int wn = wave & 1;
    const int quad = lane >> 4;
    const int lr = lane & 15;
    const int m0 = blockIdx.y * BM;
    const int n0 = blockIdx.x * BN;

    const int srow = t >> 2;
    const int scol = (t & 3) * 8;
    const int arow0 = min(m0 + srow, M - 1);
    const int arow1 = min(m0 + 64 + srow, M - 1);
    const int brow0 = n0 + srow;
    const int brow1 = n0 + 64 + srow;

    f32x4 acc[4][4] = {};

    for (int k0 = 0; k0 < D; k0 += BK) {
        gload16(A + (size_t)arow0 * D + k0 + scol, As + t * 8);
        gload16(A + (size_t)arow1 * D + k0 + scol, As + 2048 + t * 8);
        gload16(B + (size_t)brow0 * D + k0 + scol, Bs + t * 8);
        gload16(B + (size_t)brow1 * D + k0 + scol, Bs + 2048 + t * 8);
        __syncthreads();

        bf16x8 af[4], bfr[4];
        #pragma unroll
        for (int i = 0; i < 4; ++i) {
            af[i]  = *(const bf16x8*)&As[(wm * 64 + i * 16 + lr) * BK + quad * 8];
            bfr[i] = *(const bf16x8*)&Bs[(wn * 64 + i * 16 + lr) * BK + quad * 8];
        }
        #pragma unroll
        for (int i = 0; i < 4; ++i)
            #pragma unroll
            for (int j = 0; j < 4; ++j)
                acc[i][j] = __builtin_amdgcn_mfma_f32_16x16x32_bf16(af[i], bfr[j], acc[i][j], 0, 0, 0);
        __syncthreads();
    }

    #pragma unroll
    for (int j = 0; j < 4; ++j) {
        const int col = n0 + wn * 64 + j * 16 + lr;
        const float bv = bias[col];
        #pragma unroll
        for (int i = 0; i < 4; ++i) {
            const int rbase = m0 + wm * 64 + i * 16 + quad * 4;
            #pragma unroll
            for (int r = 0; r < 4; ++r) {
                const int row = rbase + r;
                if (row < M) out[(size_t)row * D + col] = acc[i][j][r] + bv;
            }
        }
    }
}

extern "C" void kernel_launch(void* const* d_in, const int* in_sizes, int n_in,
                              void* d_out, int out_size, void* d_ws, size_t ws_size,
                              hipStream_t stream) {
    const float* src_h = (const float*)d_in[0];
    const float* W     = (const float*)d_in[1];
    const float* b     = (const float*)d_in[2];
    const int*   si    = (const int*)d_in[3];
    const int*   di    = (const int*)d_in[4];
    const int M = in_sizes[0] / D;   // 50000
    const int E = in_sizes[3];       // 150000
    const int NB = (M + SB - 1) / SB; // 98 scan blocks

    char* ws = (char*)d_ws;
    unsigned short* aggb = (unsigned short*)ws;                    // M*D*2   = 51,200,000
    unsigned short* wb   = (unsigned short*)(ws + 51200000);       // D*D*2   =    524,288
    int* offsets         = (int*)(ws + 51724288);                  // (M+1)*4 =    200,004
    int* cnt             = (int*)(ws + 51924480);                  // M*4     =    200,000
    int* ssrc            = (int*)(ws + 52124480);                  // E*4     =    600,000
    int* bsum            = (int*)(ws + 52724480);                  // NB*4
    int* bscan           = (int*)(ws + 52726480);                  // NB*4

    hipMemsetAsync(cnt, 0, (size_t)M * sizeof(int), stream);
    wconv_kernel<<<dim3((D * D / 2) / 256), 256, 0, stream>>>(W, wb);
    hist_kernel<<<dim3((E + 255) / 256), 256, 0, stream>>>(di, E, cnt);
    scan_reduce_kernel<<<dim3(NB), 256, 0, stream>>>(cnt, M, bsum);
    scan_bsum_kernel<<<1, 256, 0, stream>>>(bsum, NB, bscan, offsets, M);
    scan_final_kernel<<<dim3(NB), 256, 0, stream>>>(cnt, M, bscan, offsets);
    sort_kernel<<<dim3((E + 255) / 256), 256, 0, stream>>>(si, di, E, cnt, ssrc);
    agg_kernel<<<dim3(M), 128, 0, stream>>>(src_h, offsets, ssrc, aggb);
    gemm_kernel<<<dim3(D / BN, (M + BM - 1) / BM), 256, 0, stream>>>(aggb, wb, b, (float*)d_out, M);
}

// Round 4
// 309.591 us; speedup vs baseline: 4.1317x; 1.0142x over previous
//
#include <hip/hip_runtime.h>
#include <hip/hip_bf16.h>

#define D 512
#define BM 128
#define BN 128
#define BK 32
#define SB 512          // elements per scan block

typedef __attribute__((ext_vector_type(8))) short bf16x8;
typedef __attribute__((ext_vector_type(4))) float f32x4;

__device__ __forceinline__ unsigned short bf16_rne(float f) {
    union { float f; unsigned u; } v; v.f = f;
    return (unsigned short)((v.u + 0x7FFFu + ((v.u >> 16) & 1u)) >> 16);
}

__device__ __forceinline__ void gload16(const void* g, void* l) {
    __builtin_amdgcn_global_load_lds(
        (const __attribute__((address_space(1))) void*)g,
        (__attribute__((address_space(3))) void*)l,
        16, 0, 0);
}

// ---------------- CSR build ----------------

__global__ __launch_bounds__(256) void hist_kernel(const int* __restrict__ dst, int E,
                                                   int* __restrict__ cnt) {
    int e = blockIdx.x * 256 + threadIdx.x;
    if (e < E) atomicAdd(&cnt[dst[e]], 1);
}

__global__ __launch_bounds__(256) void scan_reduce_kernel(const int* __restrict__ cnt, int M,
                                                          int* __restrict__ bsum) {
    const int t = threadIdx.x;
    const int i0 = blockIdx.x * SB + t * 2;
    int v = 0;
    if (i0 < M)     v += cnt[i0];
    if (i0 + 1 < M) v += cnt[i0 + 1];
    #pragma unroll
    for (int o = 32; o > 0; o >>= 1) v += __shfl_down(v, o, 64);
    __shared__ int ws_[4];
    if ((t & 63) == 0) ws_[t >> 6] = v;
    __syncthreads();
    if (t == 0) bsum[blockIdx.x] = ws_[0] + ws_[1] + ws_[2] + ws_[3];
}

__global__ __launch_bounds__(256) void scan_bsum_kernel(const int* __restrict__ bsum, int NB,
                                                        int* __restrict__ bscan,
                                                        int* __restrict__ offsets, int M) {
    __shared__ int s[256];
    const int t = threadIdx.x;
    int v = (t < NB) ? bsum[t] : 0;
    s[t] = v;
    __syncthreads();
    #pragma unroll
    for (int o = 1; o < 256; o <<= 1) {
        int u = (t >= o) ? s[t - o] : 0;
        __syncthreads();
        s[t] += u;
        __syncthreads();
    }
    if (t < NB) bscan[t] = s[t] - v;
    if (t == 255) offsets[M] = s[255];
}

__global__ __launch_bounds__(256) void scan_final_kernel(int* __restrict__ cnt, int M,
                                                         const int* __restrict__ bscan,
                                                         int* __restrict__ offsets) {
    __shared__ int s[256];
    const int t = threadIdx.x;
    const int base = blockIdx.x * SB + t * 2;
    int a = (base < M) ? cnt[base] : 0;
    int b = (base + 1 < M) ? cnt[base + 1] : 0;
    const int tsum = a + b;
    s[t] = tsum;
    __syncthreads();
    #pragma unroll
    for (int o = 1; o < 256; o <<= 1) {
        int u = (t >= o) ? s[t - o] : 0;
        __syncthreads();
        s[t] += u;
        __syncthreads();
    }
    const int excl = s[t] - tsum + bscan[blockIdx.x];
    if (base < M)     { offsets[base] = excl;         cnt[base] = excl; }
    if (base + 1 < M) { offsets[base + 1] = excl + a; cnt[base + 1] = excl + a; }
}

__global__ __launch_bounds__(256) void sort_kernel(const int* __restrict__ src,
                                                   const int* __restrict__ dst, int E,
                                                   int* __restrict__ cursor,
                                                   int* __restrict__ sorted_src) {
    int e = blockIdx.x * 256 + threadIdx.x;
    if (e < E) {
        int pos = atomicAdd(&cursor[dst[e]], 1);
        sorted_src[pos] = src[e];
    }
}

// ---------------- gather-aggregate (no atomics), fp32 acc -> bf16 write ----------------

__global__ __launch_bounds__(128) void agg_kernel(const float* __restrict__ src_h,
                                                  const int* __restrict__ offsets,
                                                  const int* __restrict__ sorted_src,
                                                  unsigned short* __restrict__ aggb) {
    const int d = blockIdx.x;
    const int t = threadIdx.x;
    const int beg = offsets[d];
    const int end = offsets[d + 1];
    float4 acc = {0.f, 0.f, 0.f, 0.f};
    for (int e = beg; e < end; ++e) {
        const int s = sorted_src[e];
        float4 v = ((const float4*)(src_h + (size_t)s * D))[t];
        acc.x += v.x; acc.y += v.y; acc.z += v.z; acc.w += v.w;
    }
    ushort4 o;
    o.x = bf16_rne(acc.x); o.y = bf16_rne(acc.y);
    o.z = bf16_rne(acc.z); o.w = bf16_rne(acc.w);
    *(ushort4*)(aggb + (size_t)d * D + t * 4) = o;
}

// ---------------- W fp32 -> bf16 ----------------

__global__ __launch_bounds__(256) void wconv_kernel(const float* __restrict__ W,
                                                    unsigned short* __restrict__ wb) {
    int i = blockIdx.x * 256 + threadIdx.x;
    float2 v = ((const float2*)W)[i];
    unsigned r = ((unsigned)bf16_rne(v.x)) | (((unsigned)bf16_rne(v.y)) << 16);
    ((unsigned*)wb)[i] = r;
}

// ---------------- GEMM: out = aggb @ wb^T + bias ----------------
// LDS layout XOR-swizzled: element (row, kc) stored at slot kc ^ ((row>>1)&3)
// (16B slots). Staging DMA stays lane-contiguous; fragment reads hit each
// 128B bank period exactly twice per 16 lanes -> conflict-free (2-way).
// Grid is 1D, swizzled so the 4 n-blocks of one m-tile share an XCD (%8
// round-robin) for A-tile L2 reuse.

__global__ __launch_bounds__(256) void gemm_kernel(const unsigned short* __restrict__ A,
                                                   const unsigned short* __restrict__ B,
                                                   const float* __restrict__ bias,
                                                   float* __restrict__ out,
                                                   int M, int MB_tiles) {
    __shared__ __align__(16) unsigned short As[BM * BK];
    __shared__ __align__(16) unsigned short Bs[BN * BK];

    const int L = blockIdx.x;
    const int mb = (L >> 5) * 8 + (L & 7);   // blocks differing in nb differ by 8 -> same XCD
    const int nb = (L >> 3) & 3;
    if (mb >= MB_tiles) return;
    const int m0 = mb * BM;
    const int n0 = nb * BN;

    const int t = threadIdx.x;
    const int lane = t & 63;
    const int wave = t >> 6;
    const int wm = wave >> 1;
    const int wn = wave & 1;
    const int quad = lane >> 4;
    const int lr = lane & 15;

    // staging: thread t fills LDS offset t*16B = (row = t>>2, slot = t&3);
    // the k-chunk that lives in that slot is kc = slot ^ ((row>>1)&3)
    const int srow = t >> 2;
    const int scol = ((t & 3) ^ ((t >> 3) & 3)) * 8;
    const int arow0 = min(m0 + srow, M - 1);
    const int arow1 = min(m0 + 64 + srow, M - 1);
    const int brow0 = n0 + srow;
    const int brow1 = n0 + 64 + srow;

    // fragment read swizzle: slot = quad ^ ((r>>1)&3); r%16 == lr so this is lane-only
    const int fsw = (quad ^ ((lr >> 1) & 3)) * 8;

    f32x4 acc[4][4] = {};

    for (int k0 = 0; k0 < D; k0 += BK) {
        gload16(A + (size_t)arow0 * D + k0 + scol, As + t * 8);
        gload16(A + (size_t)arow1 * D + k0 + scol, As + 2048 + t * 8);
        gload16(B + (size_t)brow0 * D + k0 + scol, Bs + t * 8);
        gload16(B + (size_t)brow1 * D + k0 + scol, Bs + 2048 + t * 8);
        __syncthreads();

        bf16x8 af[4], bfr[4];
        #pragma unroll
        for (int i = 0; i < 4; ++i) {
            af[i]  = *(const bf16x8*)&As[(wm * 64 + i * 16 + lr) * BK + fsw];
            bfr[i] = *(const bf16x8*)&Bs[(wn * 64 + i * 16 + lr) * BK + fsw];
        }
        #pragma unroll
        for (int i = 0; i < 4; ++i)
            #pragma unroll
            for (int j = 0; j < 4; ++j)
                acc[i][j] = __builtin_amdgcn_mfma_f32_16x16x32_bf16(af[i], bfr[j], acc[i][j], 0, 0, 0);
        __syncthreads();
    }

    #pragma unroll
    for (int j = 0; j < 4; ++j) {
        const int col = n0 + wn * 64 + j * 16 + lr;
        const float bv = bias[col];
        #pragma unroll
        for (int i = 0; i < 4; ++i) {
            const int rbase = m0 + wm * 64 + i * 16 + quad * 4;
            #pragma unroll
            for (int r = 0; r < 4; ++r) {
                const int row = rbase + r;
                if (row < M) out[(size_t)row * D + col] = acc[i][j][r] + bv;
            }
        }
    }
}

extern "C" void kernel_launch(void* const* d_in, const int* in_sizes, int n_in,
                              void* d_out, int out_size, void* d_ws, size_t ws_size,
                              hipStream_t stream) {
    const float* src_h = (const float*)d_in[0];
    const float* W     = (const float*)d_in[1];
    const float* b     = (const float*)d_in[2];
    const int*   si    = (const int*)d_in[3];
    const int*   di    = (const int*)d_in[4];
    const int M = in_sizes[0] / D;    // 50000
    const int E = in_sizes[3];        // 150000
    const int NB = (M + SB - 1) / SB; // scan blocks

    char* ws = (char*)d_ws;
    unsigned short* aggb = (unsigned short*)ws;                    // M*D*2
    unsigned short* wb   = (unsigned short*)(ws + 51200000);       // D*D*2
    int* offsets         = (int*)(ws + 51724288);                  // (M+1)*4
    int* cnt             = (int*)(ws + 51924480);                  // M*4
    int* ssrc            = (int*)(ws + 52124480);                  // E*4
    int* bsum            = (int*)(ws + 52724480);                  // NB*4
    int* bscan           = (int*)(ws + 52726480);                  // NB*4

    hipMemsetAsync(cnt, 0, (size_t)M * sizeof(int), stream);
    wconv_kernel<<<dim3((D * D / 2) / 256), 256, 0, stream>>>(W, wb);
    hist_kernel<<<dim3((E + 255) / 256), 256, 0, stream>>>(di, E, cnt);
    scan_reduce_kernel<<<dim3(NB), 256, 0, stream>>>(cnt, M, bsum);
    scan_bsum_kernel<<<1, 256, 0, stream>>>(bsum, NB, bscan, offsets, M);
    scan_final_kernel<<<dim3(NB), 256, 0, stream>>>(cnt, M, bscan, offsets);
    sort_kernel<<<dim3((E + 255) / 256), 256, 0, stream>>>(si, di, E, cnt, ssrc);
    agg_kernel<<<dim3(M), 128, 0, stream>>>(src_h, offsets, ssrc, aggb);

    const int MB_tiles = (M + BM - 1) / BM;                 // 391
    const int ngrid = ((MB_tiles + 7) / 8) * 32;            // 8 m-tiles x 4 n-tiles per group
    gemm_kernel<<<dim3(ngrid), 256, 0, stream>>>(aggb, wb, b, (float*)d_out, M, MB_tiles);
}